// Round 1
// baseline (292.348 us; speedup 1.0000x reference)
//
#include <hip/hip_runtime.h>
#include <stdint.h>

typedef __attribute__((ext_vector_type(8))) short bf16x8;
typedef __attribute__((ext_vector_type(4))) float f32x4;
typedef __attribute__((ext_vector_type(4))) unsigned int u32x4;

#define NB 2
#define NL 2048
#define ND 768
#define NH 12
#define NDK 64
#define NM 4096   // NB*NL

__device__ __forceinline__ unsigned short f2bf(float f) {
  unsigned u = __builtin_bit_cast(unsigned, f);
  u += 0x7FFFu + ((u >> 16) & 1u);          // RNE
  return (unsigned short)(u >> 16);
}

// ---- T5 relative-position bias table: bias_tab[h][d+2047], d = k - q ----
// bucket boundaries done with exact integer thresholds (== floor(2*log2(n)-6))
__global__ void k_bias(const float* __restrict__ rel_emb, float* __restrict__ bias_tab) {
  int idx = blockIdx.x * 256 + threadIdx.x;
  if (idx >= 4095 * NH) return;
  int h = idx % NH;
  int di = idx / NH;
  int rel = di - 2047;          // rel = k - q
  int n = -rel;
  int ret = 0;
  if (n < 0) { ret = 16; n = -n; }
  int b;
  if (n < 8) {
    b = ret + n;
  } else {
    int v = (n >= 91) ? 7 : (n >= 64) ? 6 : (n >= 46) ? 5 : (n >= 32) ? 4
          : (n >= 23) ? 3 : (n >= 16) ? 2 : (n >= 12) ? 1 : 0;
    b = ret + 8 + v;            // min(8+v,15) implied: v<=7
  }
  bias_tab[h * 4095 + di] = rel_emb[b * NH + h];
}

// ---- fp32 -> bf16 (vectorized), optional scale ----
__global__ void k_conv(const float* __restrict__ src, unsigned short* __restrict__ dst,
                       int n4, float scale) {
  int i = blockIdx.x * 256 + threadIdx.x;
  if (i >= n4) return;
  float4 v = ((const float4*)src)[i];
  ushort4 o;
  o.x = f2bf(v.x * scale);
  o.y = f2bf(v.y * scale);
  o.z = f2bf(v.z * scale);
  o.w = f2bf(v.w * scale);
  ((ushort4*)dst)[i] = o;
}

// ---- W [K][N] fp32 -> Wt [N][K] bf16 (768x768), 4 matrices selected by z ----
__global__ void k_wt(const float* __restrict__ w0, const float* __restrict__ w1,
                     const float* __restrict__ w2, const float* __restrict__ w3,
                     unsigned short* __restrict__ o0, unsigned short* __restrict__ o1,
                     unsigned short* __restrict__ o2, unsigned short* __restrict__ o3) {
  const float* w = (blockIdx.z == 0) ? w0 : (blockIdx.z == 1) ? w1 : (blockIdx.z == 2) ? w2 : w3;
  unsigned short* o = (blockIdx.z == 0) ? o0 : (blockIdx.z == 1) ? o1 : (blockIdx.z == 2) ? o2 : o3;
  __shared__ float t[32][33];
  int bx = blockIdx.x * 32, by = blockIdx.y * 32;
  int tx = threadIdx.x, ty = threadIdx.y;
  for (int r = 0; r < 32; r += 8)
    t[ty + r][tx] = w[(by + ty + r) * ND + bx + tx];
  __syncthreads();
  for (int r = 0; r < 32; r += 8)
    o[(bx + ty + r) * ND + by + tx] = f2bf(t[tx][ty + r]);
}

// ---- bf16 MFMA GEMM: C[M,N] = A[M,K] * Bt[N,K]^T. 128x128 tile, BK=32, 4 waves.
// mode 0: bf16 row-major out; 1: fp32 row-major out; 2: bf16 Vt out [B][768][L]
__global__ __launch_bounds__(256) void k_gemm(const unsigned short* __restrict__ A,
                                              const unsigned short* __restrict__ Bt,
                                              void* __restrict__ Cout,
                                              int Msz, int Nsz, int Ksz, int mode) {
  __shared__ unsigned short As[128][40];   // +8 pad: keeps 16B align, kills conflicts
  __shared__ unsigned short Bs[128][40];
  int tid = threadIdx.x;
  int wave = tid >> 6, lane = tid & 63;
  int lr = lane & 15, lg = lane >> 4;
  int m0 = blockIdx.x * 128, n0 = blockIdx.y * 128;
  int wm = (wave >> 1) * 64, wn = (wave & 1) * 64;
  f32x4 acc[4][4] = {};
  for (int k0 = 0; k0 < Ksz; k0 += 32) {
#pragma unroll
    for (int r = 0; r < 2; ++r) {
      int idx = tid + r * 256;
      int row = idx >> 2, ch = (idx & 3) * 8;
      *(u32x4*)&As[row][ch] = *(const u32x4*)&A[(size_t)(m0 + row) * Ksz + k0 + ch];
      *(u32x4*)&Bs[row][ch] = *(const u32x4*)&Bt[(size_t)(n0 + row) * Ksz + k0 + ch];
    }
    __syncthreads();
    bf16x8 af[4], bfr[4];
#pragma unroll
    for (int i = 0; i < 4; ++i) {
      af[i]  = *(const bf16x8*)&As[wm + i * 16 + lr][lg * 8];
      bfr[i] = *(const bf16x8*)&Bs[wn + i * 16 + lr][lg * 8];
    }
#pragma unroll
    for (int mi = 0; mi < 4; ++mi)
#pragma unroll
      for (int ni = 0; ni < 4; ++ni)
        acc[mi][ni] = __builtin_amdgcn_mfma_f32_16x16x32_bf16(af[mi], bfr[ni], acc[mi][ni], 0, 0, 0);
    __syncthreads();
  }
#pragma unroll
  for (int mi = 0; mi < 4; ++mi)
#pragma unroll
    for (int ni = 0; ni < 4; ++ni)
#pragma unroll
      for (int r = 0; r < 4; ++r) {
        int row = m0 + wm + mi * 16 + lg * 4 + r;   // C/D: col=lane&15, row=(lane>>4)*4+reg
        int col = n0 + wn + ni * 16 + lr;
        float v = acc[mi][ni][r];
        if (mode == 0) {
          ((unsigned short*)Cout)[(size_t)row * Nsz + col] = f2bf(v);
        } else if (mode == 1) {
          ((float*)Cout)[(size_t)row * Nsz + col] = v;
        } else {
          int bb = row >> 11, l = row & 2047;       // Vt[(b*768+col)][l]
          ((unsigned short*)Cout)[(((size_t)bb * ND + col) << 11) + l] = f2bf(v);
        }
      }
}

// ---- fused flash attention, one (b,h,128-row q-tile) per block, 4 waves x 32 rows
__global__ __launch_bounds__(256) void k_attn(const unsigned short* __restrict__ Qb,
                                              const unsigned short* __restrict__ Kb,
                                              const unsigned short* __restrict__ Vt,
                                              const float* __restrict__ bias_tab,
                                              const int* __restrict__ mask,
                                              unsigned short* __restrict__ Ob) {
  __shared__ unsigned short Ks[64][72];
  __shared__ unsigned short Vs[64][72];   // Vs[dk][key]
  __shared__ unsigned short Ps[128][72];
  __shared__ float biasr[4096];
  int qt = blockIdx.x, bh = blockIdx.y;
  int b = bh / NH, h = bh % NH;
  int tid = threadIdx.x, wave = tid >> 6, lane = tid & 63;
  int lr = lane & 15, lg = lane >> 4;
  for (int i = tid; i < 4095; i += 256) biasr[i] = bias_tab[h * 4095 + i];
  bf16x8 aq[2][2];
  int q0 = qt * 128 + wave * 32;
#pragma unroll
  for (int mi = 0; mi < 2; ++mi)
#pragma unroll
    for (int ks = 0; ks < 2; ++ks)
      aq[mi][ks] = *(const bf16x8*)&Qb[(size_t)(b * NL + q0 + mi * 16 + lr) * ND + h * NDK + ks * 32 + lg * 8];
  f32x4 accO[2][4] = {};
  float mst[2][4], lst[2][4];
#pragma unroll
  for (int mi = 0; mi < 2; ++mi)
#pragma unroll
    for (int r = 0; r < 4; ++r) { mst[mi][r] = -1e30f; lst[mi][r] = 0.f; }
  __syncthreads();
  for (int kt = 0; kt < NL / 64; ++kt) {
    int srow = tid >> 3, sch = (tid & 7) * 8;
#pragma unroll
    for (int r = 0; r < 2; ++r) {
      int rr = srow + r * 32;
      *(u32x4*)&Ks[rr][sch] = *(const u32x4*)&Kb[(size_t)(b * NL + kt * 64 + rr) * ND + h * NDK + sch];
      *(u32x4*)&Vs[rr][sch] = *(const u32x4*)&Vt[((size_t)(b * NH + h) * NDK + rr) * NL + kt * 64 + sch];
    }
    __syncthreads();
    bf16x8 bk[4][2];
#pragma unroll
    for (int ni = 0; ni < 4; ++ni) {
      bk[ni][0] = *(const bf16x8*)&Ks[ni * 16 + lr][lg * 8];
      bk[ni][1] = *(const bf16x8*)&Ks[ni * 16 + lr][32 + lg * 8];
    }
    f32x4 s[2][4];
#pragma unroll
    for (int mi = 0; mi < 2; ++mi)
#pragma unroll
      for (int ni = 0; ni < 4; ++ni) {
        f32x4 z = {0.f, 0.f, 0.f, 0.f};
        z = __builtin_amdgcn_mfma_f32_16x16x32_bf16(aq[mi][0], bk[ni][0], z, 0, 0, 0);
        z = __builtin_amdgcn_mfma_f32_16x16x32_bf16(aq[mi][1], bk[ni][1], z, 0, 0, 0);
        s[mi][ni] = z;
      }
    // bias + padding mask
#pragma unroll
    for (int ni = 0; ni < 4; ++ni) {
      int kg = kt * 64 + ni * 16 + lr;
      int mk = mask[b * NL + kg];
#pragma unroll
      for (int mi = 0; mi < 2; ++mi)
#pragma unroll
        for (int r = 0; r < 4; ++r) {
          int qg = q0 + mi * 16 + lg * 4 + r;
          float sv = s[mi][ni][r] + biasr[kg - qg + 2047];
          s[mi][ni][r] = (mk == 0) ? -1e30f : sv;
        }
    }
    // online softmax (rows live in 16-lane quarter-groups)
#pragma unroll
    for (int mi = 0; mi < 2; ++mi) {
#pragma unroll
      for (int r = 0; r < 4; ++r) {
        float v = fmaxf(fmaxf(s[mi][0][r], s[mi][1][r]), fmaxf(s[mi][2][r], s[mi][3][r]));
        v = fmaxf(v, __shfl_xor(v, 1));
        v = fmaxf(v, __shfl_xor(v, 2));
        v = fmaxf(v, __shfl_xor(v, 4));
        v = fmaxf(v, __shfl_xor(v, 8));
        float mnew = fmaxf(mst[mi][r], v);
        float sc = __expf(mst[mi][r] - mnew);
        mst[mi][r] = mnew;
        lst[mi][r] *= sc;
#pragma unroll
        for (int ni = 0; ni < 4; ++ni) accO[mi][ni][r] *= sc;
        float ps = 0.f;
#pragma unroll
        for (int ni = 0; ni < 4; ++ni) {
          float p = __expf(s[mi][ni][r] - mnew);
          s[mi][ni][r] = p;
          ps += p;
        }
        ps += __shfl_xor(ps, 1);
        ps += __shfl_xor(ps, 2);
        ps += __shfl_xor(ps, 4);
        ps += __shfl_xor(ps, 8);
        lst[mi][r] += ps;
      }
#pragma unroll
      for (int ni = 0; ni < 4; ++ni)
#pragma unroll
        for (int r = 0; r < 4; ++r)
          Ps[wave * 32 + mi * 16 + lg * 4 + r][ni * 16 + lr] = f2bf(s[mi][ni][r]);
    }
    // cross-lane LDS exchange: barrier (per-thread alias analysis can't order it)
    __syncthreads();
    // O += P @ V
#pragma unroll
    for (int mi = 0; mi < 2; ++mi)
#pragma unroll
      for (int ks = 0; ks < 2; ++ks) {
        bf16x8 ap = *(const bf16x8*)&Ps[wave * 32 + mi * 16 + lr][ks * 32 + lg * 8];
#pragma unroll
        for (int ni = 0; ni < 4; ++ni) {
          bf16x8 bv = *(const bf16x8*)&Vs[ni * 16 + lr][ks * 32 + lg * 8];
          accO[mi][ni] = __builtin_amdgcn_mfma_f32_16x16x32_bf16(ap, bv, accO[mi][ni], 0, 0, 0);
        }
      }
    __syncthreads();
  }
#pragma unroll
  for (int mi = 0; mi < 2; ++mi)
#pragma unroll
    for (int ni = 0; ni < 4; ++ni)
#pragma unroll
      for (int r = 0; r < 4; ++r) {
        int qg = q0 + mi * 16 + lg * 4 + r;
        int col = h * NDK + ni * 16 + lr;
        float v = accO[mi][ni][r] / lst[mi][r];
        Ob[(size_t)(b * NL + qg) * ND + col] = f2bf(v);
      }
}

extern "C" void kernel_launch(void* const* d_in, const int* in_sizes, int n_in,
                              void* d_out, int out_size, void* d_ws, size_t ws_size,
                              hipStream_t stream) {
  const float* query  = (const float*)d_in[0];
  const float* keyval = (const float*)d_in[1];
  const int*   mask   = (const int*)d_in[2];
  const float* Wq     = (const float*)d_in[3];
  const float* Wk     = (const float*)d_in[4];
  const float* Wv     = (const float*)d_in[5];
  const float* Wo     = (const float*)d_in[6];
  const float* rel    = (const float*)d_in[7];

  char* ws = (char*)d_ws;
  unsigned short* q_bf  = (unsigned short*)(ws);              // 4096x768 bf16 (query*0.125)
  unsigned short* kv_bf = (unsigned short*)(ws + 6291456);
  unsigned short* Wq_t  = (unsigned short*)(ws + 12582912);   // [N][K] bf16
  unsigned short* Wk_t  = (unsigned short*)(ws + 13762560);
  unsigned short* Wv_t  = (unsigned short*)(ws + 14942208);
  unsigned short* Wo_t  = (unsigned short*)(ws + 16121856);
  unsigned short* Qb    = (unsigned short*)(ws + 17301504);   // [B,L,H,DK]
  unsigned short* Kb    = (unsigned short*)(ws + 23592960);
  unsigned short* Vt    = (unsigned short*)(ws + 29884416);   // [B,768,L] (== [B,H,DK,L])
  unsigned short* Ob    = (unsigned short*)(ws + 36175872);   // [B,L,H*DK]
  float* bias_tab       = (float*)(ws + 42467328);            // [H][4095]

  k_bias<<<dim3(192), dim3(256), 0, stream>>>(rel, bias_tab);
  k_conv<<<dim3(3072), dim3(256), 0, stream>>>(query, q_bf, 786432, 0.125f);
  k_conv<<<dim3(3072), dim3(256), 0, stream>>>(keyval, kv_bf, 786432, 1.0f);
  k_wt<<<dim3(24, 24, 4), dim3(32, 8), 0, stream>>>(Wq, Wk, Wv, Wo, Wq_t, Wk_t, Wv_t, Wo_t);
  k_gemm<<<dim3(32, 6), dim3(256), 0, stream>>>(q_bf,  Wq_t, (void*)Qb, NM, ND, ND, 0);
  k_gemm<<<dim3(32, 6), dim3(256), 0, stream>>>(kv_bf, Wk_t, (void*)Kb, NM, ND, ND, 0);
  k_gemm<<<dim3(32, 6), dim3(256), 0, stream>>>(kv_bf, Wv_t, (void*)Vt, NM, ND, ND, 2);
  k_attn<<<dim3(16, 24), dim3(256), 0, stream>>>(Qb, Kb, Vt, bias_tab, mask, Ob);
  k_gemm<<<dim3(32, 6), dim3(256), 0, stream>>>(Ob, Wo_t, d_out, NM, ND, ND, 1);
}

// Round 2
// 207.520 us; speedup vs baseline: 1.4088x; 1.4088x over previous
//
#include <hip/hip_runtime.h>
#include <stdint.h>

typedef __attribute__((ext_vector_type(8))) short bf16x8;
typedef __attribute__((ext_vector_type(4))) float f32x4;
typedef __attribute__((ext_vector_type(4))) unsigned int u32x4;

#define NB 2
#define NL 2048
#define ND 768
#define NH 12
#define NDK 64
#define NM 4096   // NB*NL

__device__ __forceinline__ unsigned short f2bf(float f) {
  unsigned u = __builtin_bit_cast(unsigned, f);
  u += 0x7FFFu + ((u >> 16) & 1u);          // RNE
  return (unsigned short)(u >> 16);
}

// ---- T5 relative-position bias table: bias_tab[h][d+2047], d = k - q ----
// bucket boundaries done with exact integer thresholds (== floor(2*log2(n)-6))
__global__ void k_bias(const float* __restrict__ rel_emb, float* __restrict__ bias_tab) {
  int idx = blockIdx.x * 256 + threadIdx.x;
  if (idx >= 4095 * NH) return;
  int h = idx % NH;
  int di = idx / NH;
  int rel = di - 2047;          // rel = k - q
  int n = -rel;
  int ret = 0;
  if (n < 0) { ret = 16; n = -n; }
  int b;
  if (n < 8) {
    b = ret + n;
  } else {
    int v = (n >= 91) ? 7 : (n >= 64) ? 6 : (n >= 46) ? 5 : (n >= 32) ? 4
          : (n >= 23) ? 3 : (n >= 16) ? 2 : (n >= 12) ? 1 : 0;
    b = ret + 8 + v;            // min(8+v,15) implied: v<=7
  }
  bias_tab[h * 4095 + di] = rel_emb[b * NH + h];
}

// ---- fp32 -> bf16 (vectorized), optional scale ----
__global__ void k_conv(const float* __restrict__ src, unsigned short* __restrict__ dst,
                       int n4, float scale) {
  int i = blockIdx.x * 256 + threadIdx.x;
  if (i >= n4) return;
  float4 v = ((const float4*)src)[i];
  ushort4 o;
  o.x = f2bf(v.x * scale);
  o.y = f2bf(v.y * scale);
  o.z = f2bf(v.z * scale);
  o.w = f2bf(v.w * scale);
  ((ushort4*)dst)[i] = o;
}

// ---- W [K][N] fp32 -> Wt [N][K] bf16 (768x768), 4 matrices selected by z ----
__global__ void k_wt(const float* __restrict__ w0, const float* __restrict__ w1,
                     const float* __restrict__ w2, const float* __restrict__ w3,
                     unsigned short* __restrict__ o0, unsigned short* __restrict__ o1,
                     unsigned short* __restrict__ o2, unsigned short* __restrict__ o3) {
  const float* w = (blockIdx.z == 0) ? w0 : (blockIdx.z == 1) ? w1 : (blockIdx.z == 2) ? w2 : w3;
  unsigned short* o = (blockIdx.z == 0) ? o0 : (blockIdx.z == 1) ? o1 : (blockIdx.z == 2) ? o2 : o3;
  __shared__ float t[32][33];
  int bx = blockIdx.x * 32, by = blockIdx.y * 32;
  int tx = threadIdx.x, ty = threadIdx.y;
  for (int r = 0; r < 32; r += 8)
    t[ty + r][tx] = w[(by + ty + r) * ND + bx + tx];
  __syncthreads();
  for (int r = 0; r < 32; r += 8)
    o[(bx + ty + r) * ND + by + tx] = f2bf(t[tx][ty + r]);
}

// ---- bf16 MFMA GEMM: C[M,N] = A[M,K] * Bt[N,K]^T. 128x64 tile, BK=32, 4 waves.
// mode 0: bf16 row-major out; 1: fp32 row-major out; 2: bf16 Vt out [B][768][L]
__global__ __launch_bounds__(256) void k_gemm(const unsigned short* __restrict__ A,
                                              const unsigned short* __restrict__ Bt,
                                              void* __restrict__ Cout,
                                              int Msz, int Nsz, int Ksz, int mode) {
  __shared__ unsigned short As[128][40];   // +8 pad: keeps 16B align, kills conflicts
  __shared__ unsigned short Bs[64][40];
  int tid = threadIdx.x;
  int wave = tid >> 6, lane = tid & 63;
  int lr = lane & 15, lg = lane >> 4;
  int m0 = blockIdx.x * 128, n0 = blockIdx.y * 64;
  int wm = (wave >> 1) * 64, wn = (wave & 1) * 32;
  f32x4 acc[4][2] = {};
  for (int k0 = 0; k0 < Ksz; k0 += 32) {
#pragma unroll
    for (int r = 0; r < 2; ++r) {
      int idx = tid + r * 256;
      int row = idx >> 2, ch = (idx & 3) * 8;
      *(u32x4*)&As[row][ch] = *(const u32x4*)&A[(size_t)(m0 + row) * Ksz + k0 + ch];
    }
    {
      int row = tid >> 2, ch = (tid & 3) * 8;
      *(u32x4*)&Bs[row][ch] = *(const u32x4*)&Bt[(size_t)(n0 + row) * Ksz + k0 + ch];
    }
    __syncthreads();
    bf16x8 af[4], bfr[2];
#pragma unroll
    for (int i = 0; i < 4; ++i)
      af[i] = *(const bf16x8*)&As[wm + i * 16 + lr][lg * 8];
#pragma unroll
    for (int i = 0; i < 2; ++i)
      bfr[i] = *(const bf16x8*)&Bs[wn + i * 16 + lr][lg * 8];
#pragma unroll
    for (int mi = 0; mi < 4; ++mi)
#pragma unroll
      for (int ni = 0; ni < 2; ++ni)
        acc[mi][ni] = __builtin_amdgcn_mfma_f32_16x16x32_bf16(af[mi], bfr[ni], acc[mi][ni], 0, 0, 0);
    __syncthreads();
  }
#pragma unroll
  for (int mi = 0; mi < 4; ++mi)
#pragma unroll
    for (int ni = 0; ni < 2; ++ni)
#pragma unroll
      for (int r = 0; r < 4; ++r) {
        int row = m0 + wm + mi * 16 + lg * 4 + r;   // C/D: col=lane&15, row=(lane>>4)*4+reg
        int col = n0 + wn + ni * 16 + lr;
        float v = acc[mi][ni][r];
        if (mode == 0) {
          ((unsigned short*)Cout)[(size_t)row * Nsz + col] = f2bf(v);
        } else if (mode == 1) {
          ((float*)Cout)[(size_t)row * Nsz + col] = v;
        } else {
          int bb = row >> 11, l = row & 2047;       // Vt[(b*768+col)][l]
          ((unsigned short*)Cout)[(((size_t)bb * ND + col) << 11) + l] = f2bf(v);
        }
      }
}

// ---- fused flash attention: one (b,h,64-row q-tile) per block, 4 waves x 16 rows
__global__ __launch_bounds__(256) void k_attn(const unsigned short* __restrict__ Qb,
                                              const unsigned short* __restrict__ Kb,
                                              const unsigned short* __restrict__ Vt,
                                              const float* __restrict__ bias_tab,
                                              const int* __restrict__ mask,
                                              unsigned short* __restrict__ Ob) {
  __shared__ unsigned short Ks[64][72];
  __shared__ unsigned short Vs[64][72];   // Vs[dk][key]
  __shared__ unsigned short Ps[64][72];
  __shared__ float biasw[2112];           // window: biasw[kg - ql + 63], ql = local q row
  int qt = blockIdx.x, bh = blockIdx.y;
  int b = bh / NH, h = bh % NH;
  int tid = threadIdx.x, wave = tid >> 6, lane = tid & 63;
  int lr = lane & 15, lg = lane >> 4;
  int q0 = qt * 64;
  // bias window: global idx = kg - qg + 2047 = (1984 - q0) + (kg - ql + 63)
  for (int i = tid; i < 2111; i += 256) biasw[i] = bias_tab[h * 4095 + (1984 - q0) + i];
  bf16x8 aq[2];
  int qw = q0 + wave * 16;
#pragma unroll
  for (int ks = 0; ks < 2; ++ks)
    aq[ks] = *(const bf16x8*)&Qb[(size_t)(b * NL + qw + lr) * ND + h * NDK + ks * 32 + lg * 8];
  f32x4 accO[4] = {};
  float mst[4], lst[4];
#pragma unroll
  for (int r = 0; r < 4; ++r) { mst[r] = -1e30f; lst[r] = 0.f; }
  for (int kt = 0; kt < NL / 64; ++kt) {
    int srow = tid >> 3, sch = (tid & 7) * 8;
#pragma unroll
    for (int r = 0; r < 2; ++r) {
      int rr = srow + r * 32;
      *(u32x4*)&Ks[rr][sch] = *(const u32x4*)&Kb[(size_t)(b * NL + kt * 64 + rr) * ND + h * NDK + sch];
      *(u32x4*)&Vs[rr][sch] = *(const u32x4*)&Vt[((size_t)(b * NH + h) * NDK + rr) * NL + kt * 64 + sch];
    }
    __syncthreads();
    bf16x8 bk[4][2];
#pragma unroll
    for (int ni = 0; ni < 4; ++ni) {
      bk[ni][0] = *(const bf16x8*)&Ks[ni * 16 + lr][lg * 8];
      bk[ni][1] = *(const bf16x8*)&Ks[ni * 16 + lr][32 + lg * 8];
    }
    f32x4 s[4];
#pragma unroll
    for (int ni = 0; ni < 4; ++ni) {
      f32x4 z = {0.f, 0.f, 0.f, 0.f};
      z = __builtin_amdgcn_mfma_f32_16x16x32_bf16(aq[0], bk[ni][0], z, 0, 0, 0);
      z = __builtin_amdgcn_mfma_f32_16x16x32_bf16(aq[1], bk[ni][1], z, 0, 0, 0);
      s[ni] = z;
    }
    // bias + padding mask
#pragma unroll
    for (int ni = 0; ni < 4; ++ni) {
      int kg = kt * 64 + ni * 16 + lr;
      int mk = mask[b * NL + kg];
#pragma unroll
      for (int r = 0; r < 4; ++r) {
        int ql = wave * 16 + lg * 4 + r;
        float sv = s[ni][r] + biasw[kg - ql + 63];
        s[ni][r] = (mk == 0) ? -1e30f : sv;
      }
    }
    // online softmax (each q-row lives in a 16-lane group; r selects the row)
#pragma unroll
    for (int r = 0; r < 4; ++r) {
      float v = fmaxf(fmaxf(s[0][r], s[1][r]), fmaxf(s[2][r], s[3][r]));
      v = fmaxf(v, __shfl_xor(v, 1));
      v = fmaxf(v, __shfl_xor(v, 2));
      v = fmaxf(v, __shfl_xor(v, 4));
      v = fmaxf(v, __shfl_xor(v, 8));
      float mnew = fmaxf(mst[r], v);
      float sc = __expf(mst[r] - mnew);
      mst[r] = mnew;
      lst[r] *= sc;
#pragma unroll
      for (int ni = 0; ni < 4; ++ni) accO[ni][r] *= sc;
      float ps = 0.f;
#pragma unroll
      for (int ni = 0; ni < 4; ++ni) {
        float p = __expf(s[ni][r] - mnew);
        s[ni][r] = p;
        ps += p;
      }
      ps += __shfl_xor(ps, 1);
      ps += __shfl_xor(ps, 2);
      ps += __shfl_xor(ps, 4);
      ps += __shfl_xor(ps, 8);
      lst[r] += ps;
    }
#pragma unroll
    for (int ni = 0; ni < 4; ++ni)
#pragma unroll
      for (int r = 0; r < 4; ++r)
        Ps[wave * 16 + lg * 4 + r][ni * 16 + lr] = f2bf(s[ni][r]);
    // cross-lane LDS exchange: barrier (per-thread alias analysis can't order it)
    __syncthreads();
    // O += P @ V
#pragma unroll
    for (int ks = 0; ks < 2; ++ks) {
      bf16x8 ap = *(const bf16x8*)&Ps[wave * 16 + lr][ks * 32 + lg * 8];
#pragma unroll
      for (int ni = 0; ni < 4; ++ni) {
        bf16x8 bv = *(const bf16x8*)&Vs[ni * 16 + lr][ks * 32 + lg * 8];
        accO[ni] = __builtin_amdgcn_mfma_f32_16x16x32_bf16(ap, bv, accO[ni], 0, 0, 0);
      }
    }
    __syncthreads();
  }
#pragma unroll
  for (int ni = 0; ni < 4; ++ni)
#pragma unroll
    for (int r = 0; r < 4; ++r) {
      int qg = qw + lg * 4 + r;
      int col = h * NDK + ni * 16 + lr;
      float v = accO[ni][r] / lst[r];
      Ob[(size_t)(b * NL + qg) * ND + col] = f2bf(v);
    }
}

extern "C" void kernel_launch(void* const* d_in, const int* in_sizes, int n_in,
                              void* d_out, int out_size, void* d_ws, size_t ws_size,
                              hipStream_t stream) {
  const float* query  = (const float*)d_in[0];
  const float* keyval = (const float*)d_in[1];
  const int*   mask   = (const int*)d_in[2];
  const float* Wq     = (const float*)d_in[3];
  const float* Wk     = (const float*)d_in[4];
  const float* Wv     = (const float*)d_in[5];
  const float* Wo     = (const float*)d_in[6];
  const float* rel    = (const float*)d_in[7];

  char* ws = (char*)d_ws;
  unsigned short* q_bf  = (unsigned short*)(ws);              // 4096x768 bf16 (query*0.125)
  unsigned short* kv_bf = (unsigned short*)(ws + 6291456);
  unsigned short* Wq_t  = (unsigned short*)(ws + 12582912);   // [N][K] bf16
  unsigned short* Wk_t  = (unsigned short*)(ws + 13762560);
  unsigned short* Wv_t  = (unsigned short*)(ws + 14942208);
  unsigned short* Wo_t  = (unsigned short*)(ws + 16121856);
  unsigned short* Qb    = (unsigned short*)(ws + 17301504);   // [B,L,H,DK]
  unsigned short* Kb    = (unsigned short*)(ws + 23592960);
  unsigned short* Vt    = (unsigned short*)(ws + 29884416);   // [B,768,L] (== [B,H,DK,L])
  unsigned short* Ob    = (unsigned short*)(ws + 36175872);   // [B,L,H*DK]
  float* bias_tab       = (float*)(ws + 42467328);            // [H][4095]

  k_bias<<<dim3(192), dim3(256), 0, stream>>>(rel, bias_tab);
  k_conv<<<dim3(3072), dim3(256), 0, stream>>>(query, q_bf, 786432, 0.125f);
  k_conv<<<dim3(3072), dim3(256), 0, stream>>>(keyval, kv_bf, 786432, 1.0f);
  k_wt<<<dim3(24, 24, 4), dim3(32, 8), 0, stream>>>(Wq, Wk, Wv, Wo, Wq_t, Wk_t, Wv_t, Wo_t);
  k_gemm<<<dim3(32, 12), dim3(256), 0, stream>>>(q_bf,  Wq_t, (void*)Qb, NM, ND, ND, 0);
  k_gemm<<<dim3(32, 12), dim3(256), 0, stream>>>(kv_bf, Wk_t, (void*)Kb, NM, ND, ND, 0);
  k_gemm<<<dim3(32, 12), dim3(256), 0, stream>>>(kv_bf, Wv_t, (void*)Vt, NM, ND, ND, 2);
  k_attn<<<dim3(32, 24), dim3(256), 0, stream>>>(Qb, Kb, Vt, bias_tab, mask, Ob);
  k_gemm<<<dim3(32, 12), dim3(256), 0, stream>>>(Ob, Wo_t, d_out, NM, ND, ND, 1);
}